// Round 8
// baseline (183.281 us; speedup 1.0000x reference)
//
#include <hip/hip_runtime.h>
#include <math.h>

// ProbSparse attention (Informer). B=2 L=4096 H=8 D=64, U_part=u=45.
// R7: k_attn latency fixes. Phase1: 4-way split accumulators (dep chain
// 256->64 cy per dot). Phase2: DPP row_shr/row_bcast reductions on the VALU
// pipe instead of 6-step ds_bpermute butterflies; wave-uniform via readlane.
// scoreM untouched (at per-XCD L2-BW roofline: 94 MB / 2.2 TB/s ~= 43 us).
#define JAX_PARTITIONABLE 1

constexpr int Bc = 2, Lc = 4096, Hc = 8, Dc = 64;
constexpr int BHc = Bc * Hc;     // 16
constexpr int Uc = 45;           // top-k queries
constexpr int NSc = 45;          // samples per query

typedef float vfloat4 __attribute__((ext_vector_type(4)));

struct TF2 { unsigned a, b; };

__host__ __device__ constexpr unsigned rotl32(unsigned v, int n) {
  return (v << n) | (v >> (32 - n));
}

// Threefry-2x32, 20 rounds (JAX reference schedule).
__host__ __device__ constexpr TF2 tf2(unsigned k0, unsigned k1, unsigned x0, unsigned x1) {
  unsigned ks2 = k0 ^ k1 ^ 0x1BD11BDAu;
  x0 += k0; x1 += k1;
  x0 += x1; x1 = rotl32(x1, 13); x1 ^= x0;
  x0 += x1; x1 = rotl32(x1, 15); x1 ^= x0;
  x0 += x1; x1 = rotl32(x1, 26); x1 ^= x0;
  x0 += x1; x1 = rotl32(x1, 6);  x1 ^= x0;
  x0 += k1; x1 += ks2 + 1u;
  x0 += x1; x1 = rotl32(x1, 17); x1 ^= x0;
  x0 += x1; x1 = rotl32(x1, 29); x1 ^= x0;
  x0 += x1; x1 = rotl32(x1, 16); x1 ^= x0;
  x0 += x1; x1 = rotl32(x1, 24); x1 ^= x0;
  x0 += ks2; x1 += k0 + 2u;
  x0 += x1; x1 = rotl32(x1, 13); x1 ^= x0;
  x0 += x1; x1 = rotl32(x1, 15); x1 ^= x0;
  x0 += x1; x1 = rotl32(x1, 26); x1 ^= x0;
  x0 += x1; x1 = rotl32(x1, 6);  x1 ^= x0;
  x0 += k0; x1 += k1 + 3u;
  x0 += x1; x1 = rotl32(x1, 17); x1 ^= x0;
  x0 += x1; x1 = rotl32(x1, 29); x1 ^= x0;
  x0 += x1; x1 = rotl32(x1, 16); x1 ^= x0;
  x0 += x1; x1 = rotl32(x1, 24); x1 ^= x0;
  x0 += k1; x1 += ks2 + 4u;
  x0 += x1; x1 = rotl32(x1, 13); x1 ^= x0;
  x0 += x1; x1 = rotl32(x1, 15); x1 ^= x0;
  x0 += x1; x1 = rotl32(x1, 26); x1 ^= x0;
  x0 += x1; x1 = rotl32(x1, 6);  x1 ^= x0;
  x0 += ks2; x1 += k0 + 5u;
  return TF2{x0, x1};
}

// VALU-pipe partial-sum add via DPP (identity old=0 for invalid lanes).
template <int CTRL>
__device__ __forceinline__ float dpp_add(float x) {
  int t = __builtin_amdgcn_update_dpp(0, __float_as_int(x), CTRL, 0xF, 0xF, false);
  return x + __int_as_float(t);
}
// DPP-shifted value with own value as identity for invalid lanes (for max).
template <int CTRL>
__device__ __forceinline__ float dpp_idf(float x) {
  int t = __builtin_amdgcn_update_dpp(__float_as_int(x), __float_as_int(x), CTRL, 0xF, 0xF, false);
  return __int_as_float(t);
}
// Full-wave (64-lane) max/sum: result valid at lane 63, broadcast via readlane.
__device__ __forceinline__ float wave_max_bcast(float x) {
  x = fmaxf(x, dpp_idf<0x111>(x));   // row_shr:1
  x = fmaxf(x, dpp_idf<0x112>(x));   // row_shr:2
  x = fmaxf(x, dpp_idf<0x114>(x));   // row_shr:4
  x = fmaxf(x, dpp_idf<0x118>(x));   // row_shr:8  -> lane15 of each row = row max
  x = fmaxf(x, dpp_idf<0x142>(x));   // row_bcast:15
  x = fmaxf(x, dpp_idf<0x143>(x));   // row_bcast:31 -> lane63 = wave max
  return __int_as_float(__builtin_amdgcn_readlane(__float_as_int(x), 63));
}
__device__ __forceinline__ float wave_sum_bcast(float x) {
  x = dpp_add<0x111>(x);
  x = dpp_add<0x112>(x);
  x = dpp_add<0x114>(x);
  x = dpp_add<0x118>(x);
  x = dpp_add<0x142>(x);
  x = dpp_add<0x143>(x);
  return __int_as_float(__builtin_amdgcn_readlane(__float_as_int(x), 63));
}

// M[bh][q] = max_s dot(Q[q],K[idx[q][s]]) - sum_s(...)/4096.
// bh = blockIdx&15: with round-robin block->XCD dispatch, each XCD sees 2 bh
// -> 2 MB K slices stay L2-resident. At per-XCD L2-BW roofline (~43 us).
__global__ __launch_bounds__(256) void k_scoreM(const float* __restrict__ Q, const float* __restrict__ K,
                                                float* __restrict__ M) {
  __shared__ int sidx[720];
  int tid = threadIdx.x;
  int bx = blockIdx.x;
  int bh = bx & 15;
  int qblk = bx >> 4;              // 0..255
  int b = bh >> 3, h = bh & 7;
  int lane16 = tid & 15, qloc = tid >> 4;
  int q = qblk * 16 + qloc;
  constexpr TF2 kb = tf2(0u, 1u, 0u, 1u);
  for (int e = tid; e < 720; e += 256) {
    TF2 r = tf2(kb.a, kb.b, 0u, (unsigned)(qblk * 720 + e));
    sidx[e] = (int)((r.a ^ r.b) & 4095u);
  }
  __syncthreads();
  const vfloat4* Q4 = (const vfloat4*)Q;
  const vfloat4* K4 = (const vfloat4*)K;
  vfloat4 qr = Q4[((b * Lc + q) * Hc + h) * 16 + lane16];
  int kbase = (b * Lc * Hc + h) * 16 + lane16;
  const int* ip = sidx + qloc * NSc;
  float mx = -INFINITY, sm = 0.f;
  #pragma unroll
  for (int s0 = 0; s0 < NSc; s0 += 5) {      // 5-deep load batch: L2 loads in flight
    int kk[5];
    #pragma unroll
    for (int i = 0; i < 5; ++i) kk[i] = ip[s0 + i];
    vfloat4 kv[5];
    #pragma unroll
    for (int i = 0; i < 5; ++i) kv[i] = __builtin_nontemporal_load(&K4[kbase + kk[i] * (Hc * 16)]);
    #pragma unroll
    for (int i = 0; i < 5; ++i) {
      float p = qr[0] * kv[i][0] + qr[1] * kv[i][1] + qr[2] * kv[i][2] + qr[3] * kv[i][3];
      p = dpp_add<0x111>(p);                 // row_shr cascade -> lane15 = full dot
      p = dpp_add<0x112>(p);
      p = dpp_add<0x114>(p);
      p = dpp_add<0x118>(p);
      mx = fmaxf(mx, p);                     // valid at lane15; junk elsewhere (never read)
      sm += p;
    }
  }
  if (lane16 == 15) M[bh * Lc + q] = mx - sm * (1.0f / Lc);
}

// Radix-select top-45 of 4096 per bh (exact lax.top_k: value desc, index asc
// on ties). Then pre-gather the 45 selected Q rows into qg[bh][45][64].
__global__ __launch_bounds__(256) void k_topk(const float* __restrict__ M, const float* __restrict__ Q,
                                              int* __restrict__ topk, float* __restrict__ qg) {
  __shared__ unsigned su[Lc];      // 16 KB mapped keys
  __shared__ int hist[256];
  __shared__ int sfx[257];
  __shared__ unsigned s_prefix;
  __shared__ int s_r;
  __shared__ int n_gt, n_eq;
  __shared__ unsigned cu[64];
  __shared__ int cidx[64];
  __shared__ int eqi[64];
  __shared__ int srank[Uc];
  int bh = blockIdx.x, tid = threadIdx.x;
  int b = bh >> 3, h = bh & 7;
  const float* m = M + bh * Lc;
  for (int e = tid; e < Lc; e += 256) {
    unsigned bb = __float_as_uint(m[e]);
    su[e] = (bb & 0x80000000u) ? ~bb : (bb | 0x80000000u);
  }
  if (tid == 0) { s_r = Uc; s_prefix = 0u; n_gt = 0; n_eq = 0; }
  __syncthreads();
  #pragma unroll
  for (int p = 0; p < 4; ++p) {
    int shift = 24 - 8 * p;
    hist[tid] = 0;
    __syncthreads();
    unsigned pref = s_prefix;
    unsigned hmask = (p == 0) ? 0u : (0xFFFFFFFFu << (shift + 8));
    for (int e = tid; e < Lc; e += 256) {
      unsigned u = su[e];
      if ((u & hmask) == pref) atomicAdd(&hist[(u >> shift) & 255u], 1);
    }
    __syncthreads();
    sfx[tid] = hist[tid];
    __syncthreads();
    for (int off = 1; off < 256; off <<= 1) {   // inclusive suffix sum
      int v = (tid + off < 256) ? sfx[tid + off] : 0;
      __syncthreads();
      sfx[tid] += v;
      __syncthreads();
    }
    int r = s_r;
    __syncthreads();                            // all read s_r before update
    int above = (tid < 255) ? sfx[tid + 1] : 0;
    if (sfx[tid] >= r && above < r) {           // unique digit
      s_r = r - above;
      s_prefix = pref | ((unsigned)tid << shift);
    }
    __syncthreads();
  }
  unsigned T = s_prefix;                        // exact 45th-largest key
  int rf = s_r;                                 // #equals to take (>=1)
  for (int e = tid; e < Lc; e += 256) {
    unsigned u = su[e];
    if (u > T) {
      int p = atomicAdd(&n_gt, 1);              // <= 44
      cu[p] = u; cidx[p] = e;
    } else if (u == T) {
      int p = atomicAdd(&n_eq, 1);
      if (p < 64) eqi[p] = e;                   // >64-way ties: impossible for random-normal M
    }
  }
  __syncthreads();
  int ne = n_eq < 64 ? n_eq : 64;
  if (tid < ne) {
    int myi = eqi[tid];
    int rank = 0;
    for (int j = 0; j < ne; ++j) rank += (eqi[j] < myi);
    if (rank < rf) {
      int p = atomicAdd(&n_gt, 1);              // completes to exactly 45
      cu[p] = T; cidx[p] = myi;
    }
  }
  __syncthreads();
  if (tid < Uc) {
    unsigned mu = cu[tid]; int mi = cidx[tid];
    int rank = 0;
    for (int j = 0; j < Uc; ++j) {
      unsigned ju = cu[j]; int ji = cidx[j];
      rank += (ju > mu) || (ju == mu && ji < mi);
    }
    topk[bh * Uc + rank] = mi;
    srank[rank] = mi;
  }
  __syncthreads();
  const float4* Q4 = (const float4*)Q;
  float4* qg4 = (float4*)qg;
  for (int e = tid; e < Uc * 16; e += 256) {    // coalesced pre-gather of selected Q rows
    int t = e >> 4, dq = e & 15;
    qg4[bh * Uc * 16 + e] = Q4[((b * Lc + srank[t]) * Hc + h) * 16 + dq];
  }
}

// Flash-decoding partials: one block per (bh, CH-key chunk), CH = 4096/NC.
template<int NC>
__global__ __launch_bounds__(256) void k_attn(const float* __restrict__ qg, const float* __restrict__ K,
                                              const float* __restrict__ V, const int* __restrict__ amask,
                                              float* __restrict__ pO, float* __restrict__ pM,
                                              float* __restrict__ pL) {
  constexpr int CH = Lc / NC;
  constexpr int TG = 256 / CH;
  int chunk = blockIdx.x, bh = blockIdx.y;
  int b = bh >> 3, h = bh & 7;
  int tid = threadIdx.x;
  __shared__ __align__(16) float qs[Uc * 64];
  __shared__ float sc[48][CH + 1];
  {
    const float4* qg4 = (const float4*)qg;
    float4* qs4w = (float4*)qs;
    for (int e = tid; e < Uc * 16; e += 256) qs4w[e] = qg4[bh * Uc * 16 + e];
  }
  for (int e = tid; e < 3 * CH; e += 256) sc[45 + e / CH][e % CH] = 0.f;
  __syncthreads();
  {
    int k = tid % CH, tg = tid / CH;
    int key = chunk * CH + k;
    const float4* K4 = (const float4*)K;
    int kb = ((b * Lc + key) * Hc + h) * 16;
    float4 kr[16];
    #pragma unroll
    for (int j = 0; j < 16; ++j) kr[j] = K4[kb + j];
    int mk = amask[b * Lc + key];
    const float4* qs4 = (const float4*)qs;
    for (int t = tg; t < Uc; t += TG) {
      float a0 = 0.f, a1 = 0.f, a2 = 0.f, a3 = 0.f;   // 4-way split: dep chain 256->64 cy
      #pragma unroll
      for (int j = 0; j < 16; j += 4) {
        float4 q0 = qs4[t * 16 + j],     q1 = qs4[t * 16 + j + 1];
        float4 q2 = qs4[t * 16 + j + 2], q3 = qs4[t * 16 + j + 3];
        a0 += q0.x * kr[j].x     + q0.y * kr[j].y     + q0.z * kr[j].z     + q0.w * kr[j].w;
        a1 += q1.x * kr[j + 1].x + q1.y * kr[j + 1].y + q1.z * kr[j + 1].z + q1.w * kr[j + 1].w;
        a2 += q2.x * kr[j + 2].x + q2.y * kr[j + 2].y + q2.z * kr[j + 2].z + q2.w * kr[j + 2].w;
        a3 += q3.x * kr[j + 3].x + q3.y * kr[j + 3].y + q3.z * kr[j + 3].z + q3.w * kr[j + 3].w;
      }
      float acc = (a0 + a1) + (a2 + a3);
      sc[t][k] = mk ? acc * 0.125f : -INFINITY;
    }
  }
  __syncthreads();
  {
    // NC=64 -> CH=64: one wave per score row; DPP reductions (VALU pipe).
    int w = tid >> 6, lane = tid & 63;
    for (int t = w; t < Uc; t += 4) {
      float x = sc[t][lane];
      float ml = wave_max_bcast(x);
      float p = (ml != -INFINITY) ? __expf(x - ml) : 0.f;   // fully-masked chunk guard
      sc[t][lane] = p;
      float ls = wave_sum_bcast(p);
      if (lane == 0) {
        pM[(bh * NC + chunk) * Uc + t] = ml;
        pL[(bh * NC + chunk) * Uc + t] = ls;
      }
    }
  }
  __syncthreads();
  {
    int ty = tid >> 4, tx = tid & 15;
    float4 o0 = {0.f, 0.f, 0.f, 0.f};
    float4 o1 = {0.f, 0.f, 0.f, 0.f};
    float4 o2 = {0.f, 0.f, 0.f, 0.f};
    const float4* V4 = (const float4*)V;
    int vbase = (b * Lc + chunk * CH) * (Hc * 16) + h * 16 + tx;
    #pragma unroll 4
    for (int k = 0; k < CH; ++k) {
      float4 v4 = V4[vbase + k * (Hc * 16)];
      float p0 = sc[ty][k], p1 = sc[ty + 16][k], p2 = sc[ty + 32][k];
      o0.x += p0 * v4.x; o0.y += p0 * v4.y; o0.z += p0 * v4.z; o0.w += p0 * v4.w;
      o1.x += p1 * v4.x; o1.y += p1 * v4.y; o1.z += p1 * v4.z; o1.w += p1 * v4.w;
      o2.x += p2 * v4.x; o2.y += p2 * v4.y; o2.z += p2 * v4.z; o2.w += p2 * v4.w;
    }
    float4* pO4 = (float4*)pO;
    int obase = ((bh * NC + chunk) * Uc) * 16 + tx;
    pO4[obase + ty * 16] = o0;
    pO4[obase + (ty + 16) * 16] = o1;
    if (ty < 13) pO4[obase + (ty + 32) * 16] = o2;
  }
}

// Exact merge of chunk partials; out[b][t][h][d].
template<int NC>
__global__ __launch_bounds__(256) void k_merge(const float* __restrict__ pO, const float* __restrict__ pM,
                                               const float* __restrict__ pL, float* __restrict__ out) {
  int f = blockIdx.x * 256 + threadIdx.x;   // 180*256 == 46080
  int d = f & 63, h = (f >> 6) & 7;
  int bt = f >> 9;
  int t = bt % Uc, b = bt / Uc;
  int bh = b * 8 + h;
  float m = -INFINITY;
  for (int c = 0; c < NC; ++c) m = fmaxf(m, pM[(bh * NC + c) * Uc + t]);
  float den = 0.f, num = 0.f;
  for (int c = 0; c < NC; ++c) {
    float mc = pM[(bh * NC + c) * Uc + t];
    float wgt = (mc == -INFINITY) ? 0.f : __expf(mc - m);
    den += wgt * pL[(bh * NC + c) * Uc + t];
    num += wgt * pO[((bh * NC + c) * Uc + t) * 64 + d];
  }
  out[f] = num / den;
}

extern "C" void kernel_launch(void* const* d_in, const int* in_sizes, int n_in,
                              void* d_out, int out_size, void* d_ws, size_t ws_size,
                              hipStream_t stream) {
  const float* Q = (const float*)d_in[0];
  const float* K = (const float*)d_in[1];
  const float* V = (const float*)d_in[2];
  const int* amask = (const int*)d_in[3];
  float* out = (float*)d_out;
  char* ws = (char*)d_ws;
  float* M    = (float*)(ws + 0x000000);   // 65536 floats (256 KB)
  int*   topk = (int*)(ws + 0x040000);     // 720 ints
  float* qg   = (float*)(ws + 0x041000);   // 16*45*64 floats (184,320 B)
  float* pM   = (float*)(ws + 0x070000);
  // ws_size is constant across calls -> branch is deterministic (graph-safe).
  size_t need64 = 0x70000UL + 64UL * 190080UL;   // pM+pL+pO for NC=64 (~12.6 MB)
  size_t need32 = 0x70000UL + 32UL * 190080UL;
  int NC = ws_size >= need64 ? 64 : (ws_size >= need32 ? 32 : 16);
  float* pL = pM + 16 * NC * Uc;
  float* pO = pL + 16 * NC * Uc;

  k_scoreM<<<4096, 256, 0, stream>>>(Q, K, M);
  k_topk<<<BHc, 256, 0, stream>>>(M, Q, topk, qg);
  if (NC == 64) {
    k_attn<64><<<dim3(64, BHc), 256, 0, stream>>>(qg, K, V, amask, pO, pM, pL);
    k_merge<64><<<180, 256, 0, stream>>>(pO, pM, pL, out);
  } else if (NC == 32) {
    k_attn<32><<<dim3(32, BHc), 256, 0, stream>>>(qg, K, V, amask, pO, pM, pL);
    k_merge<32><<<180, 256, 0, stream>>>(pO, pM, pL, out);
  } else {
    k_attn<16><<<dim3(16, BHc), 256, 0, stream>>>(qg, K, V, amask, pO, pM, pL);
    k_merge<16><<<180, 256, 0, stream>>>(pO, pM, pL, out);
  }
}

// Round 9
// 178.250 us; speedup vs baseline: 1.0282x; 1.0282x over previous
//
#include <hip/hip_runtime.h>
#include <math.h>

// ProbSparse attention (Informer). B=2 L=4096 H=8 D=64, U_part=u=45.
// R8: k_attn throughput fixes (R7 attacked latency - neutral). Phase1 dots
// as fmaf chains (8 -> 4 VALU insts per float4; compiler can't reassociate
// mul+add without fast-math). Phase3 p-reads vectorized to ds_read_b128
// (sc rows padded to 68 floats for 16-B alignment; 192 -> 48 LDS insts).
// scoreM dot also fmaf (tests the L2-line-rate roofline: 1.47M lines/XCD
// at ~16 lines/cy = 38 us floor -> time should NOT move).
#define JAX_PARTITIONABLE 1

constexpr int Bc = 2, Lc = 4096, Hc = 8, Dc = 64;
constexpr int BHc = Bc * Hc;     // 16
constexpr int Uc = 45;           // top-k queries
constexpr int NSc = 45;          // samples per query

typedef float vfloat4 __attribute__((ext_vector_type(4)));

struct TF2 { unsigned a, b; };

__host__ __device__ constexpr unsigned rotl32(unsigned v, int n) {
  return (v << n) | (v >> (32 - n));
}

// Threefry-2x32, 20 rounds (JAX reference schedule).
__host__ __device__ constexpr TF2 tf2(unsigned k0, unsigned k1, unsigned x0, unsigned x1) {
  unsigned ks2 = k0 ^ k1 ^ 0x1BD11BDAu;
  x0 += k0; x1 += k1;
  x0 += x1; x1 = rotl32(x1, 13); x1 ^= x0;
  x0 += x1; x1 = rotl32(x1, 15); x1 ^= x0;
  x0 += x1; x1 = rotl32(x1, 26); x1 ^= x0;
  x0 += x1; x1 = rotl32(x1, 6);  x1 ^= x0;
  x0 += k1; x1 += ks2 + 1u;
  x0 += x1; x1 = rotl32(x1, 17); x1 ^= x0;
  x0 += x1; x1 = rotl32(x1, 29); x1 ^= x0;
  x0 += x1; x1 = rotl32(x1, 16); x1 ^= x0;
  x0 += x1; x1 = rotl32(x1, 24); x1 ^= x0;
  x0 += ks2; x1 += k0 + 2u;
  x0 += x1; x1 = rotl32(x1, 13); x1 ^= x0;
  x0 += x1; x1 = rotl32(x1, 15); x1 ^= x0;
  x0 += x1; x1 = rotl32(x1, 26); x1 ^= x0;
  x0 += x1; x1 = rotl32(x1, 6);  x1 ^= x0;
  x0 += k0; x1 += k1 + 3u;
  x0 += x1; x1 = rotl32(x1, 17); x1 ^= x0;
  x0 += x1; x1 = rotl32(x1, 29); x1 ^= x0;
  x0 += x1; x1 = rotl32(x1, 16); x1 ^= x0;
  x0 += x1; x1 = rotl32(x1, 24); x1 ^= x0;
  x0 += k1; x1 += ks2 + 4u;
  x0 += x1; x1 = rotl32(x1, 13); x1 ^= x0;
  x0 += x1; x1 = rotl32(x1, 15); x1 ^= x0;
  x0 += x1; x1 = rotl32(x1, 26); x1 ^= x0;
  x0 += x1; x1 = rotl32(x1, 6);  x1 ^= x0;
  x0 += ks2; x1 += k0 + 5u;
  return TF2{x0, x1};
}

// VALU-pipe partial-sum add via DPP (identity old=0 for invalid lanes).
template <int CTRL>
__device__ __forceinline__ float dpp_add(float x) {
  int t = __builtin_amdgcn_update_dpp(0, __float_as_int(x), CTRL, 0xF, 0xF, false);
  return x + __int_as_float(t);
}
// DPP-shifted value with own value as identity for invalid lanes (for max).
template <int CTRL>
__device__ __forceinline__ float dpp_idf(float x) {
  int t = __builtin_amdgcn_update_dpp(__float_as_int(x), __float_as_int(x), CTRL, 0xF, 0xF, false);
  return __int_as_float(t);
}
// Full-wave (64-lane) max/sum: result valid at lane 63, broadcast via readlane.
__device__ __forceinline__ float wave_max_bcast(float x) {
  x = fmaxf(x, dpp_idf<0x111>(x));   // row_shr:1
  x = fmaxf(x, dpp_idf<0x112>(x));   // row_shr:2
  x = fmaxf(x, dpp_idf<0x114>(x));   // row_shr:4
  x = fmaxf(x, dpp_idf<0x118>(x));   // row_shr:8  -> lane15 of each row = row max
  x = fmaxf(x, dpp_idf<0x142>(x));   // row_bcast:15
  x = fmaxf(x, dpp_idf<0x143>(x));   // row_bcast:31 -> lane63 = wave max
  return __int_as_float(__builtin_amdgcn_readlane(__float_as_int(x), 63));
}
__device__ __forceinline__ float wave_sum_bcast(float x) {
  x = dpp_add<0x111>(x);
  x = dpp_add<0x112>(x);
  x = dpp_add<0x114>(x);
  x = dpp_add<0x118>(x);
  x = dpp_add<0x142>(x);
  x = dpp_add<0x143>(x);
  return __int_as_float(__builtin_amdgcn_readlane(__float_as_int(x), 63));
}

// fmaf chain for a float4 dot accumulated into a: 4 VALU insts.
__device__ __forceinline__ float dot4_acc(float4 q, float4 k, float a) {
  a = fmaf(q.x, k.x, a);
  a = fmaf(q.y, k.y, a);
  a = fmaf(q.z, k.z, a);
  a = fmaf(q.w, k.w, a);
  return a;
}

// M[bh][q] = max_s dot(Q[q],K[idx[q][s]]) - sum_s(...)/4096.
// bh = blockIdx&15: with round-robin block->XCD dispatch, each XCD sees 2 bh
// -> 2 MB K slices stay L2-resident. At the L2 random-line-rate roofline
// (1.47M 64-B lines/XCD @ ~16 lines/cy ~= 38 us).
__global__ __launch_bounds__(256) void k_scoreM(const float* __restrict__ Q, const float* __restrict__ K,
                                                float* __restrict__ M) {
  __shared__ int sidx[720];
  int tid = threadIdx.x;
  int bx = blockIdx.x;
  int bh = bx & 15;
  int qblk = bx >> 4;              // 0..255
  int b = bh >> 3, h = bh & 7;
  int lane16 = tid & 15, qloc = tid >> 4;
  int q = qblk * 16 + qloc;
  constexpr TF2 kb = tf2(0u, 1u, 0u, 1u);
  for (int e = tid; e < 720; e += 256) {
    TF2 r = tf2(kb.a, kb.b, 0u, (unsigned)(qblk * 720 + e));
    sidx[e] = (int)((r.a ^ r.b) & 4095u);
  }
  __syncthreads();
  const vfloat4* Q4 = (const vfloat4*)Q;
  const vfloat4* K4 = (const vfloat4*)K;
  vfloat4 qr = Q4[((b * Lc + q) * Hc + h) * 16 + lane16];
  int kbase = (b * Lc * Hc + h) * 16 + lane16;
  const int* ip = sidx + qloc * NSc;
  float mx = -INFINITY, sm = 0.f;
  #pragma unroll
  for (int s0 = 0; s0 < NSc; s0 += 5) {      // 5-deep load batch: L2 loads in flight
    int kk[5];
    #pragma unroll
    for (int i = 0; i < 5; ++i) kk[i] = ip[s0 + i];
    vfloat4 kv[5];
    #pragma unroll
    for (int i = 0; i < 5; ++i) kv[i] = __builtin_nontemporal_load(&K4[kbase + kk[i] * (Hc * 16)]);
    #pragma unroll
    for (int i = 0; i < 5; ++i) {
      float p = fmaf(qr[0], kv[i][0], fmaf(qr[1], kv[i][1], fmaf(qr[2], kv[i][2], qr[3] * kv[i][3])));
      p = dpp_add<0x111>(p);                 // row_shr cascade -> lane15 = full dot
      p = dpp_add<0x112>(p);
      p = dpp_add<0x114>(p);
      p = dpp_add<0x118>(p);
      mx = fmaxf(mx, p);                     // valid at lane15; junk elsewhere (never read)
      sm += p;
    }
  }
  if (lane16 == 15) M[bh * Lc + q] = mx - sm * (1.0f / Lc);
}

// Radix-select top-45 of 4096 per bh (exact lax.top_k: value desc, index asc
// on ties). Then pre-gather the 45 selected Q rows into qg[bh][45][64].
__global__ __launch_bounds__(256) void k_topk(const float* __restrict__ M, const float* __restrict__ Q,
                                              int* __restrict__ topk, float* __restrict__ qg) {
  __shared__ unsigned su[Lc];      // 16 KB mapped keys
  __shared__ int hist[256];
  __shared__ int sfx[257];
  __shared__ unsigned s_prefix;
  __shared__ int s_r;
  __shared__ int n_gt, n_eq;
  __shared__ unsigned cu[64];
  __shared__ int cidx[64];
  __shared__ int eqi[64];
  __shared__ int srank[Uc];
  int bh = blockIdx.x, tid = threadIdx.x;
  int b = bh >> 3, h = bh & 7;
  const float* m = M + bh * Lc;
  for (int e = tid; e < Lc; e += 256) {
    unsigned bb = __float_as_uint(m[e]);
    su[e] = (bb & 0x80000000u) ? ~bb : (bb | 0x80000000u);
  }
  if (tid == 0) { s_r = Uc; s_prefix = 0u; n_gt = 0; n_eq = 0; }
  __syncthreads();
  #pragma unroll
  for (int p = 0; p < 4; ++p) {
    int shift = 24 - 8 * p;
    hist[tid] = 0;
    __syncthreads();
    unsigned pref = s_prefix;
    unsigned hmask = (p == 0) ? 0u : (0xFFFFFFFFu << (shift + 8));
    for (int e = tid; e < Lc; e += 256) {
      unsigned u = su[e];
      if ((u & hmask) == pref) atomicAdd(&hist[(u >> shift) & 255u], 1);
    }
    __syncthreads();
    sfx[tid] = hist[tid];
    __syncthreads();
    for (int off = 1; off < 256; off <<= 1) {   // inclusive suffix sum
      int v = (tid + off < 256) ? sfx[tid + off] : 0;
      __syncthreads();
      sfx[tid] += v;
      __syncthreads();
    }
    int r = s_r;
    __syncthreads();                            // all read s_r before update
    int above = (tid < 255) ? sfx[tid + 1] : 0;
    if (sfx[tid] >= r && above < r) {           // unique digit
      s_r = r - above;
      s_prefix = pref | ((unsigned)tid << shift);
    }
    __syncthreads();
  }
  unsigned T = s_prefix;                        // exact 45th-largest key
  int rf = s_r;                                 // #equals to take (>=1)
  for (int e = tid; e < Lc; e += 256) {
    unsigned u = su[e];
    if (u > T) {
      int p = atomicAdd(&n_gt, 1);              // <= 44
      cu[p] = u; cidx[p] = e;
    } else if (u == T) {
      int p = atomicAdd(&n_eq, 1);
      if (p < 64) eqi[p] = e;                   // >64-way ties: impossible for random-normal M
    }
  }
  __syncthreads();
  int ne = n_eq < 64 ? n_eq : 64;
  if (tid < ne) {
    int myi = eqi[tid];
    int rank = 0;
    for (int j = 0; j < ne; ++j) rank += (eqi[j] < myi);
    if (rank < rf) {
      int p = atomicAdd(&n_gt, 1);              // completes to exactly 45
      cu[p] = T; cidx[p] = myi;
    }
  }
  __syncthreads();
  if (tid < Uc) {
    unsigned mu = cu[tid]; int mi = cidx[tid];
    int rank = 0;
    for (int j = 0; j < Uc; ++j) {
      unsigned ju = cu[j]; int ji = cidx[j];
      rank += (ju > mu) || (ju == mu && ji < mi);
    }
    topk[bh * Uc + rank] = mi;
    srank[rank] = mi;
  }
  __syncthreads();
  const float4* Q4 = (const float4*)Q;
  float4* qg4 = (float4*)qg;
  for (int e = tid; e < Uc * 16; e += 256) {    // coalesced pre-gather of selected Q rows
    int t = e >> 4, dq = e & 15;
    qg4[bh * Uc * 16 + e] = Q4[((b * Lc + srank[t]) * Hc + h) * 16 + dq];
  }
}

// Flash-decoding partials: one block per (bh, CH-key chunk), CH = 4096/NC.
// NOTE: phase 2 assumes CH == 64 (one wave per score row); the NC=64 path is
// always taken in practice (ws_size >> 13 MB).
template<int NC>
__global__ __launch_bounds__(256) void k_attn(const float* __restrict__ qg, const float* __restrict__ K,
                                              const float* __restrict__ V, const int* __restrict__ amask,
                                              float* __restrict__ pO, float* __restrict__ pM,
                                              float* __restrict__ pL) {
  constexpr int CH = Lc / NC;
  constexpr int TG = 256 / CH;
  constexpr int SCW = CH + 4;      // row stride 68 floats = 272 B (16-B aligned rows)
  int chunk = blockIdx.x, bh = blockIdx.y;
  int b = bh >> 3, h = bh & 7;
  int tid = threadIdx.x;
  __shared__ __align__(16) float qs[Uc * 64];
  __shared__ __align__(16) float sc[48][SCW];
  {
    const float4* qg4 = (const float4*)qg;
    float4* qs4w = (float4*)qs;
    for (int e = tid; e < Uc * 16; e += 256) qs4w[e] = qg4[bh * Uc * 16 + e];
  }
  for (int e = tid; e < 3 * SCW; e += 256) sc[45 + e / SCW][e % SCW] = 0.f;
  __syncthreads();
  {
    int k = tid % CH, tg = tid / CH;
    int key = chunk * CH + k;
    const float4* K4 = (const float4*)K;
    int kb = ((b * Lc + key) * Hc + h) * 16;
    float4 kr[16];
    #pragma unroll
    for (int j = 0; j < 16; ++j) kr[j] = K4[kb + j];
    int mk = amask[b * Lc + key];
    const float4* qs4 = (const float4*)qs;
    for (int t = tg; t < Uc; t += TG) {
      float a0 = 0.f, a1 = 0.f, a2 = 0.f, a3 = 0.f;   // 4 independent fmaf chains
      #pragma unroll
      for (int j = 0; j < 16; j += 4) {
        a0 = dot4_acc(qs4[t * 16 + j],     kr[j],     a0);
        a1 = dot4_acc(qs4[t * 16 + j + 1], kr[j + 1], a1);
        a2 = dot4_acc(qs4[t * 16 + j + 2], kr[j + 2], a2);
        a3 = dot4_acc(qs4[t * 16 + j + 3], kr[j + 3], a3);
      }
      float acc = (a0 + a1) + (a2 + a3);
      sc[t][k] = mk ? acc * 0.125f : -INFINITY;
    }
  }
  __syncthreads();
  {
    // CH=64: one wave per score row; DPP reductions (VALU pipe).
    int w = tid >> 6, lane = tid & 63;
    for (int t = w; t < Uc; t += 4) {
      float x = sc[t][lane];
      float ml = wave_max_bcast(x);
      float p = (ml != -INFINITY) ? __expf(x - ml) : 0.f;   // fully-masked chunk guard
      sc[t][lane] = p;
      float ls = wave_sum_bcast(p);
      if (lane == 0) {
        pM[(bh * NC + chunk) * Uc + t] = ml;
        pL[(bh * NC + chunk) * Uc + t] = ls;
      }
    }
  }
  __syncthreads();
  {
    int ty = tid >> 4, tx = tid & 15;
    float4 o0 = {0.f, 0.f, 0.f, 0.f};
    float4 o1 = {0.f, 0.f, 0.f, 0.f};
    float4 o2 = {0.f, 0.f, 0.f, 0.f};
    const float4* V4 = (const float4*)V;
    const float4* s0 = (const float4*)&sc[ty][0];        // rows 16-B aligned (SCW=68)
    const float4* s1 = (const float4*)&sc[ty + 16][0];
    const float4* s2 = (const float4*)&sc[ty + 32][0];
    int vbase = (b * Lc + chunk * CH) * (Hc * 16) + h * 16 + tx;
    #pragma unroll 2
    for (int kq = 0; kq < CH / 4; ++kq) {
      float4 p0 = s0[kq], p1 = s1[kq], p2 = s2[kq];      // 4 keys per ds_read_b128
      float4 va = V4[vbase + (4 * kq + 0) * (Hc * 16)];
      float4 vb = V4[vbase + (4 * kq + 1) * (Hc * 16)];
      float4 vc = V4[vbase + (4 * kq + 2) * (Hc * 16)];
      float4 vd = V4[vbase + (4 * kq + 3) * (Hc * 16)];
      o0.x = fmaf(p0.x, va.x, o0.x); o0.y = fmaf(p0.x, va.y, o0.y); o0.z = fmaf(p0.x, va.z, o0.z); o0.w = fmaf(p0.x, va.w, o0.w);
      o1.x = fmaf(p1.x, va.x, o1.x); o1.y = fmaf(p1.x, va.y, o1.y); o1.z = fmaf(p1.x, va.z, o1.z); o1.w = fmaf(p1.x, va.w, o1.w);
      o2.x = fmaf(p2.x, va.x, o2.x); o2.y = fmaf(p2.x, va.y, o2.y); o2.z = fmaf(p2.x, va.z, o2.z); o2.w = fmaf(p2.x, va.w, o2.w);
      o0.x = fmaf(p0.y, vb.x, o0.x); o0.y = fmaf(p0.y, vb.y, o0.y); o0.z = fmaf(p0.y, vb.z, o0.z); o0.w = fmaf(p0.y, vb.w, o0.w);
      o1.x = fmaf(p1.y, vb.x, o1.x); o1.y = fmaf(p1.y, vb.y, o1.y); o1.z = fmaf(p1.y, vb.z, o1.z); o1.w = fmaf(p1.y, vb.w, o1.w);
      o2.x = fmaf(p2.y, vb.x, o2.x); o2.y = fmaf(p2.y, vb.y, o2.y); o2.z = fmaf(p2.y, vb.z, o2.z); o2.w = fmaf(p2.y, vb.w, o2.w);
      o0.x = fmaf(p0.z, vc.x, o0.x); o0.y = fmaf(p0.z, vc.y, o0.y); o0.z = fmaf(p0.z, vc.z, o0.z); o0.w = fmaf(p0.z, vc.w, o0.w);
      o1.x = fmaf(p1.z, vc.x, o1.x); o1.y = fmaf(p1.z, vc.y, o1.y); o1.z = fmaf(p1.z, vc.z, o1.z); o1.w = fmaf(p1.z, vc.w, o1.w);
      o2.x = fmaf(p2.z, vc.x, o2.x); o2.y = fmaf(p2.z, vc.y, o2.y); o2.z = fmaf(p2.z, vc.z, o2.z); o2.w = fmaf(p2.z, vc.w, o2.w);
      o0.x = fmaf(p0.w, vd.x, o0.x); o0.y = fmaf(p0.w, vd.y, o0.y); o0.z = fmaf(p0.w, vd.z, o0.z); o0.w = fmaf(p0.w, vd.w, o0.w);
      o1.x = fmaf(p1.w, vd.x, o1.x); o1.y = fmaf(p1.w, vd.y, o1.y); o1.z = fmaf(p1.w, vd.z, o1.z); o1.w = fmaf(p1.w, vd.w, o1.w);
      o2.x = fmaf(p2.w, vd.x, o2.x); o2.y = fmaf(p2.w, vd.y, o2.y); o2.z = fmaf(p2.w, vd.z, o2.z); o2.w = fmaf(p2.w, vd.w, o2.w);
    }
    float4* pO4 = (float4*)pO;
    int obase = ((bh * NC + chunk) * Uc) * 16 + tx;
    pO4[obase + ty * 16] = o0;
    pO4[obase + (ty + 16) * 16] = o1;
    if (ty < 13) pO4[obase + (ty + 32) * 16] = o2;
  }
}

// Exact merge of chunk partials; out[b][t][h][d].
template<int NC>
__global__ __launch_bounds__(256) void k_merge(const float* __restrict__ pO, const float* __restrict__ pM,
                                               const float* __restrict__ pL, float* __restrict__ out) {
  int f = blockIdx.x * 256 + threadIdx.x;   // 180*256 == 46080
  int d = f & 63, h = (f >> 6) & 7;
  int bt = f >> 9;
  int t = bt % Uc, b = bt / Uc;
  int bh = b * 8 + h;
  float m = -INFINITY;
  for (int c = 0; c < NC; ++c) m = fmaxf(m, pM[(bh * NC + c) * Uc + t]);
  float den = 0.f, num = 0.f;
  for (int c = 0; c < NC; ++c) {
    float mc = pM[(bh * NC + c) * Uc + t];
    float wgt = (mc == -INFINITY) ? 0.f : __expf(mc - m);
    den += wgt * pL[(bh * NC + c) * Uc + t];
    num += wgt * pO[((bh * NC + c) * Uc + t) * 64 + d];
  }
  out[f] = num / den;
}

extern "C" void kernel_launch(void* const* d_in, const int* in_sizes, int n_in,
                              void* d_out, int out_size, void* d_ws, size_t ws_size,
                              hipStream_t stream) {
  const float* Q = (const float*)d_in[0];
  const float* K = (const float*)d_in[1];
  const float* V = (const float*)d_in[2];
  const int* amask = (const int*)d_in[3];
  float* out = (float*)d_out;
  char* ws = (char*)d_ws;
  float* M    = (float*)(ws + 0x000000);   // 65536 floats (256 KB)
  int*   topk = (int*)(ws + 0x040000);     // 720 ints
  float* qg   = (float*)(ws + 0x041000);   // 16*45*64 floats (184,320 B)
  float* pM   = (float*)(ws + 0x070000);
  // ws_size is constant across calls -> branch is deterministic (graph-safe).
  size_t need64 = 0x70000UL + 64UL * 190080UL;   // pM+pL+pO for NC=64 (~12.6 MB)
  size_t need32 = 0x70000UL + 32UL * 190080UL;
  int NC = ws_size >= need64 ? 64 : (ws_size >= need32 ? 32 : 16);
  float* pL = pM + 16 * NC * Uc;
  float* pO = pL + 16 * NC * Uc;

  k_scoreM<<<4096, 256, 0, stream>>>(Q, K, M);
  k_topk<<<BHc, 256, 0, stream>>>(M, Q, topk, qg);
  if (NC == 64) {
    k_attn<64><<<dim3(64, BHc), 256, 0, stream>>>(qg, K, V, amask, pO, pM, pL);
    k_merge<64><<<180, 256, 0, stream>>>(pO, pM, pL, out);
  } else if (NC == 32) {
    k_attn<32><<<dim3(32, BHc), 256, 0, stream>>>(qg, K, V, amask, pO, pM, pL);
    k_merge<32><<<180, 256, 0, stream>>>(pO, pM, pL, out);
  } else {
    k_attn<16><<<dim3(16, BHc), 256, 0, stream>>>(qg, K, V, amask, pO, pM, pL);
    k_merge<16><<<180, 256, 0, stream>>>(pO, pM, pL, out);
  }
}